// Round 8
// baseline (343.218 us; speedup 1.0000x reference)
//
#include <hip/hip_runtime.h>

// SimpleDialogGNN on MI355X.
// Pipeline (4 launches):
//   K0 prep_kernel    : fused {transpose_pack + msg_pack}
//   K1 gemm<2048,EPI1>: h = xcat @ wt_cat^T + biases; relu/substitute -> rbuf
//   K2 gemm<1024,EPI2>: z = x + rbuf @ wt_out^T + b_out -> fp32 zbuf
//   K3 ln_kernel      : LayerNorm(z) * gamma + beta -> out
//
// GEMM core (this round): r6/r7 measured LDS-pipe-bound (8.4 MB/CU through
// one 128B/cyc pipe = 75k cyc vs 33k MFMA; schedule changes were null).
// Fix: B fragments load DIRECTLY global->VGPR (weights: 512KB/block panel
// L2-resident, 8KB/body working set L1-resident); only A goes through LDS
// (3-slot rotation, 24KB/block, one async16/thread/body, stage distance 3
// issued after the body barrier). Traffic now splits across LDS (~3.1MB),
// L1/L2 (B, ~4.2MB), and MFMA pipes instead of one LDS pole.
// Geometry unchanged: 128x128 tile, 512 thr / 8 waves (32x64 C per wave),
// grid 512 = 2 blocks/CU, T1 XCD map, A swizzle (0 conflicts verified).
// Numerics bit-identical to r6/r7 (same fragments, same MFMA order).
//
// ws layout: [0,32M) xcat (bf16, aliased by zbuf fp32 after GEMM1)
//            [32M,48M) rbuf  [48M,52M) wt_cat  [52M,54M) wt_out

typedef unsigned short u16;
typedef float floatx4 __attribute__((ext_vector_type(4)));
typedef short shortx8 __attribute__((ext_vector_type(8)));

#define T_ 1024
#define H_ 1024

__device__ __forceinline__ float bf2f(u16 v) {
    return __uint_as_float(((unsigned)v) << 16);
}
__device__ __forceinline__ u16 f2bf(float f) {  // round-to-nearest-even
    unsigned u = __float_as_uint(f);
    return (u16)((u + 0x7fffu + ((u >> 16) & 1u)) >> 16);
}
__device__ __forceinline__ void async16(const void* g, void* l) {
    __builtin_amdgcn_global_load_lds(
        (__attribute__((address_space(1))) void*)g,
        (__attribute__((address_space(3))) void*)l, 16, 0, 0);
}
__device__ __forceinline__ void barrier_mem() {
    asm volatile("" ::: "memory");
    __builtin_amdgcn_s_barrier();
    asm volatile("" ::: "memory");
}

// ---------------- K0: fused weight-pack + message aggregation ----------------
__global__ __launch_bounds__(256)
void prep_kernel(const float* __restrict__ x, const float* __restrict__ qmask,
                 const int* __restrict__ dia_len,
                 const float* __restrict__ Wself, const float* __restrict__ Wmsg,
                 const float* __restrict__ Wout,
                 u16* __restrict__ xcat, u16* __restrict__ wt_cat,
                 u16* __restrict__ wt_out)
{
    __shared__ u16 sx[32][1024];  // 64 KiB (transpose path reuses a corner)
    const int tid = threadIdx.x;
    const int bx = blockIdx.x;

    if (bx >= 512) {
        // ---- transpose + bf16 pack of one 32x32 weight tile ----
        const int id = bx - 512;            // 0..3071
        const int wid = id >> 10;           // 0..2
        const int rest = id & 1023;
        const int n0 = (rest & 31) * 32, k0 = (rest >> 5) * 32;
        const float* src = (wid == 0) ? Wself : ((wid == 1) ? Wmsg : Wout);
        float (*s)[33] = reinterpret_cast<float (*)[33]>(&sx[0][0]);
        const int tx = tid & 31, ty = tid >> 5;  // 32x8
#pragma unroll
        for (int i = 0; i < 4; ++i) {
            int k = k0 + ty + 8 * i;
            s[ty + 8 * i][tx] = src[(size_t)k * H_ + n0 + tx];
        }
        __syncthreads();
#pragma unroll
        for (int i = 0; i < 4; ++i) {
            int n = n0 + ty + 8 * i;
            u16 v = f2bf(s[tx][ty + 8 * i]);
            if (wid < 2) wt_cat[(size_t)n * 2048 + wid * 1024 + k0 + tx] = v;
            else         wt_out[(size_t)n * 1024 + k0 + tx] = v;
        }
        return;
    }

    // ---- msg_pack: stage 32 rows (halo 8 each side) as bf16 in LDS ----
    const int b = bx >> 6;
    const int t0 = (bx & 63) * 16;
    const int dlen = dia_len[b];
    const int c4 = tid * 4;
    const float* xb = x + (size_t)b * T_ * H_;

    unsigned spkmask = 0;
#pragma unroll 4
    for (int r = 0; r < 32; ++r) {
        int row = t0 - 8 + r;
        row = row < 0 ? 0 : (row > T_ - 1 ? T_ - 1 : row);
        const float* q = qmask + ((size_t)b * T_ + row) * 2;
        spkmask |= (q[1] > q[0] ? 1u : 0u) << r;
        float4 v = *(const float4*)(xb + (size_t)row * H_ + c4);
        ushort4 u;
        u.x = f2bf(v.x); u.y = f2bf(v.y); u.z = f2bf(v.z); u.w = f2bf(v.w);
        *(ushort4*)&sx[r][c4] = u;
    }
    __syncthreads();

    for (int lt = 0; lt < 16; ++lt) {
        const int t = t0 + lt;
        const unsigned cs = (spkmask >> (lt + 8)) & 1u;
        float a0 = 0.f, a1 = 0.f, a2 = 0.f, a3 = 0.f;
        int cnt = 0;
#pragma unroll
        for (int o = 0; o < 17; ++o) {
            const int idx = t + o - 8;
            if (idx >= 0 && idx < dlen) {  // block-uniform branch
                const float w = (((spkmask >> (lt + o)) & 1u) == cs) ? 1.0f : 0.5f;
                ++cnt;
                ushort4 u = *(const ushort4*)&sx[lt + o][c4];
                a0 += w * bf2f(u.x); a1 += w * bf2f(u.y);
                a2 += w * bf2f(u.z); a3 += w * bf2f(u.w);
            }
        }
        const float inv = 1.0f / (float)(cnt > 0 ? cnt : 1);
        ushort4 m;
        m.x = f2bf(a0 * inv); m.y = f2bf(a1 * inv);
        m.z = f2bf(a2 * inv); m.w = f2bf(a3 * inv);
        const size_t rowg = (size_t)b * T_ + t;
        *(ushort4*)&xcat[rowg * 2048 + 1024 + c4] = m;
        *(ushort4*)&xcat[rowg * 2048 + c4] = *(const ushort4*)&sx[lt + 8][c4];
    }
}

// ---------------- K1/K2: bf16 MFMA GEMM, A-via-LDS, B-direct-from-global -----
// A: M x K row-major bf16; Bt: N x K row-major bf16 (N-major).
// A swizzle: logical (row, 16B-chunk c) at physical chunk c ^ ((row>>1)&3).

#define LOADB(BV, TT) do {                                                    \
    BV[0] = *(const shortx8*)(bBase0 + (size_t)(TT) * 32);                    \
    BV[1] = *(const shortx8*)(bBase1 + (size_t)(TT) * 32);                    \
    BV[2] = *(const shortx8*)(bBase2 + (size_t)(TT) * 32);                    \
    BV[3] = *(const shortx8*)(bBase3 + (size_t)(TT) * 32);                    \
} while (0)

#define LOADA(AV, TT) do {                                                    \
    const u16* pA_ = &sA[(TT) % 3][0];                                        \
    AV[0] = *(const shortx8*)(pA_ + aOff0);                                   \
    AV[1] = *(const shortx8*)(pA_ + aOff1);                                   \
} while (0)

#define GBODY(TT, AC, BC, AN, BNV) do {                                       \
    if ((TT) + 1 < NT) {                                                      \
        LOADB(BNV, (TT) + 1);                                                 \
        LOADA(AN, (TT) + 1);                                                  \
    }                                                                         \
    __builtin_amdgcn_sched_barrier(0);                                        \
    __builtin_amdgcn_s_setprio(1);                                            \
    acc[0][0] = __builtin_amdgcn_mfma_f32_16x16x32_bf16(AC[0], BC[0], acc[0][0], 0, 0, 0); \
    acc[1][0] = __builtin_amdgcn_mfma_f32_16x16x32_bf16(AC[1], BC[0], acc[1][0], 0, 0, 0); \
    acc[0][1] = __builtin_amdgcn_mfma_f32_16x16x32_bf16(AC[0], BC[1], acc[0][1], 0, 0, 0); \
    acc[1][1] = __builtin_amdgcn_mfma_f32_16x16x32_bf16(AC[1], BC[1], acc[1][1], 0, 0, 0); \
    acc[0][2] = __builtin_amdgcn_mfma_f32_16x16x32_bf16(AC[0], BC[2], acc[0][2], 0, 0, 0); \
    acc[1][2] = __builtin_amdgcn_mfma_f32_16x16x32_bf16(AC[1], BC[2], acc[1][2], 0, 0, 0); \
    acc[0][3] = __builtin_amdgcn_mfma_f32_16x16x32_bf16(AC[0], BC[3], acc[0][3], 0, 0, 0); \
    acc[1][3] = __builtin_amdgcn_mfma_f32_16x16x32_bf16(AC[1], BC[3], acc[1][3], 0, 0, 0); \
    __builtin_amdgcn_s_setprio(0);                                            \
    if ((TT) + 1 < NT) {                                                      \
        asm volatile("s_waitcnt vmcnt(1)" ::: "memory");                      \
        barrier_mem();                                                        \
        if ((TT) + 3 < NT) stage((TT) + 3);                                   \
    }                                                                         \
} while (0)

template <int K, int EPI>
__global__ __launch_bounds__(512, 4)
void gemm_bt(const u16* __restrict__ A, const u16* __restrict__ Bt,
             const float* __restrict__ bias1, const float* __restrict__ bias2,
             const float* __restrict__ X, const int* __restrict__ dia_len,
             u16* __restrict__ Rout, float* __restrict__ Zout)
{
    constexpr int NT = K / 32;
    static_assert(NT >= 4 && (NT & 1) == 0, "NT even, >=4");
    __shared__ u16 sA[3][128 * 32];  // 24 KiB (A only; B never touches LDS)
    const int tid = threadIdx.x;

    // T1: XCD-aware block map (verified ~ideal FETCH r3-r7).
    const int bid = blockIdx.x;
    const int xcd = bid & 7, li = bid >> 3;     // li in [0,64)
    const int mt = xcd * 8 + (li >> 3);         // 0..63
    const int nt = li & 7;                      // 0..7
    const int bm = mt * 128, bn = nt * 128;

    const int wave = tid >> 6, lane = tid & 63;
    const int wr = wave >> 1, wc = wave & 1;    // 4M x 2N waves, 32x64 C each
    const int lrow = lane & 15, lq = lane >> 4;

    // ---- A staging: 512 thr x 16B = whole 128x32 tile per async16 ----
    const int srow = tid >> 2;                  // 0..127
    const int sl   = (tid & 3) ^ ((srow >> 1) & 3);  // pre-swizzled chunk
    const u16* Asrc = A + (size_t)(bm + srow) * K + sl * 8;

    auto stage = [&](int t) {                   // 1 async16 per thread
        async16(Asrc + (size_t)t * 32, &sA[t % 3][tid * 8]);
    };

    // ---- B: direct global->VGPR fragment pointers (per lane) ----
    const u16* bBase0 = Bt + (size_t)(bn + wc * 64 +  0 + lrow) * K + lq * 8;
    const u16* bBase1 = Bt + (size_t)(bn + wc * 64 + 16 + lrow) * K + lq * 8;
    const u16* bBase2 = Bt + (size_t)(bn + wc * 64 + 32 + lrow) * K + lq * 8;
    const u16* bBase3 = Bt + (size_t)(bn + wc * 64 + 48 + lrow) * K + lq * 8;

    floatx4 acc[2][4];
#pragma unroll
    for (int i = 0; i < 2; ++i)
#pragma unroll
        for (int j = 0; j < 4; ++j)
            acc[i][j] = (floatx4){0.f, 0.f, 0.f, 0.f};

    // ---- compute-side A offsets (loop-invariant, swizzled) ----
    const int ra0 = wr * 32 + lrow, ra1 = ra0 + 16;
    const int aOff0 = ra0 * 32 + (lq ^ ((ra0 >> 1) & 3)) * 8;
    const int aOff1 = ra1 * 32 + (lq ^ ((ra1 >> 1) & 3)) * 8;

    // ---- prologue: A slots 0..2 in flight, B(0) in regs, drain once ----
    stage(0); stage(1); stage(2);
    shortx8 aP[2], bP[4], aQ[2], bQ[4];
    LOADB(bP, 0);
    asm volatile("s_waitcnt vmcnt(0)" ::: "memory");
    barrier_mem();
    LOADA(aP, 0);

    for (int t = 0; t < NT; t += 2) {
        GBODY(t,     aP, bP, aQ, bQ);
        GBODY(t + 1, aQ, bQ, aP, bP);
    }

    // epilogue — C/D mapping: col = lane&15, row = (lane>>4)*4 + reg
    const int dl = (EPI == 1) ? dia_len[bm >> 10] : 0;  // b uniform per block
#pragma unroll
    for (int i = 0; i < 2; ++i) {
        const int row0 = bm + wr * 32 + i * 16 + lq * 4;
#pragma unroll
        for (int j = 0; j < 4; ++j) {
            const int col = bn + wc * 64 + j * 16 + lrow;
#pragma unroll
            for (int r = 0; r < 4; ++r) {
                const int row = row0 + r;
                const float v = acc[i][j][r];
                if (EPI == 1) {
                    const float h = v + bias1[col] + bias2[col];
                    float outv;
                    if ((row & (T_ - 1)) < dl) {
                        outv = h;  // majority path: no X read
                    } else {
                        outv = X[(size_t)row * H_ + col];
                    }
                    Rout[(size_t)row * H_ + col] = f2bf(fmaxf(outv, 0.f));
                } else {
                    const float z = X[(size_t)row * H_ + col] + v + bias1[col];
                    Zout[(size_t)row * H_ + col] = z;
                }
            }
        }
    }
}

// ---------------- K3: LayerNorm ---------------------------------------------
__global__ __launch_bounds__(256)
void ln_kernel(const float* __restrict__ Z, const float* __restrict__ gamma,
               const float* __restrict__ beta, float* __restrict__ out)
{
    const int row = blockIdx.x;
    const int tid = threadIdx.x;
    const size_t base = (size_t)row * H_ + tid * 4;
    float4 v = *(const float4*)(Z + base);
    float s = v.x + v.y + v.z + v.w;
    float q = v.x * v.x + v.y * v.y + v.z * v.z + v.w * v.w;
#pragma unroll
    for (int off = 32; off > 0; off >>= 1) {
        s += __shfl_down(s, off);
        q += __shfl_down(q, off);
    }
    __shared__ float ps[4], pq[4];
    const int wave = tid >> 6, lane = tid & 63;
    if (lane == 0) { ps[wave] = s; pq[wave] = q; }
    __syncthreads();
    const float S = ps[0] + ps[1] + ps[2] + ps[3];
    const float Q = pq[0] + pq[1] + pq[2] + pq[3];
    const float mean = S * (1.0f / 1024.0f);
    const float var = Q * (1.0f / 1024.0f) - mean * mean;
    const float inv = rsqrtf(var + 1e-5f);
    float4 g = *(const float4*)(gamma + tid * 4);
    float4 bt = *(const float4*)(beta + tid * 4);
    float4 o;
    o.x = g.x * (v.x - mean) * inv + bt.x;
    o.y = g.y * (v.y - mean) * inv + bt.y;
    o.z = g.z * (v.z - mean) * inv + bt.z;
    o.w = g.w * (v.w - mean) * inv + bt.w;
    *(float4*)(out + base) = o;
}

// ---------------- launcher ---------------------------------------------------
extern "C" void kernel_launch(void* const* d_in, const int* in_sizes, int n_in,
                              void* d_out, int out_size, void* d_ws, size_t ws_size,
                              hipStream_t stream)
{
    (void)in_sizes; (void)n_in; (void)out_size; (void)ws_size;
    const float* x       = (const float*)d_in[0];
    const float* qmask   = (const float*)d_in[1];
    const int*   dia_len = (const int*)d_in[2];
    const float* W_msg   = (const float*)d_in[5];
    const float* b_msg   = (const float*)d_in[6];
    const float* W_self  = (const float*)d_in[7];
    const float* b_self  = (const float*)d_in[8];
    const float* W_out   = (const float*)d_in[9];
    const float* b_out   = (const float*)d_in[10];
    const float* gamma   = (const float*)d_in[11];
    const float* beta    = (const float*)d_in[12];
    float* out = (float*)d_out;

    char* ws = (char*)d_ws;
    u16*   xcat   = (u16*)ws;                           // 32 MiB
    u16*   rbuf   = (u16*)(ws + (size_t)(32u << 20));   // 16 MiB
    u16*   wt_cat = (u16*)(ws + (size_t)(48u << 20));   // 4 MiB
    u16*   wt_out = (u16*)(ws + (size_t)(52u << 20));   // 2 MiB
    float* zbuf   = (float*)ws;                         // alias xcat (safe: GEMM2 no longer reads xcat)

    prep_kernel<<<dim3(3584), 256, 0, stream>>>(x, qmask, dia_len,
                                                W_self, W_msg, W_out,
                                                xcat, wt_cat, wt_out);
    gemm_bt<2048, 1><<<dim3(512), 512, 0, stream>>>(xcat, wt_cat, b_self, b_msg,
                                                    x, dia_len, rbuf, nullptr);
    gemm_bt<1024, 2><<<dim3(512), 512, 0, stream>>>(rbuf, wt_out, b_out, nullptr,
                                                    x, nullptr, nullptr, zbuf);
    ln_kernel<<<dim3(8192), 256, 0, stream>>>(zbuf, gamma, beta, out);
}

// Round 10
// 203.586 us; speedup vs baseline: 1.6859x; 1.6859x over previous
//
#include <hip/hip_runtime.h>

// SimpleDialogGNN on MI355X.
// Pipeline (4 launches):
//   K0 prep_kernel    : fused {transpose_pack + msg_pack}
//   K1 gemm<2048,EPI1>: h = xcat @ wt_cat^T + biases; relu/substitute -> rbuf
//   K2 gemm<1024,EPI2>: z = x + rbuf @ wt_out^T + b_out -> fp32 zbuf
//   K3 ln_kernel      : LayerNorm(z) * gamma + beta -> out
//
// GEMM K-loop: EXACT r6 structure (best measured: 48.3us, MfmaUtil 29%):
// 128x128 tile, 512 thr / 8 waves (32x64 C each), BK=64, 2-slot dbuf,
// stage-at-top, one vmcnt(0)+barrier per tile, T2 swizzle (0 conflicts),
// T1 XCD map (FETCH ~ideal), grid 512 = 2 blocks/CU.
//
// Epilogue: restage C through LDS so all global I/O is full-line coalesced.
// r9 BUG FIX: epilogue barriers MUST be __syncthreads() (s_waitcnt
// lgkmcnt(0) + s_barrier). r9 used bare s_barrier: writer waves' ds_writes
// were still in flight when reader waves ds_read the tile -> race ->
// wrong output. K-loop barriers unchanged (vmcnt-tracked, proven in r6).
//
// ws layout: [0,32M) xcat (bf16, aliased by zbuf fp32 after GEMM1)
//            [32M,48M) rbuf  [48M,52M) wt_cat  [52M,54M) wt_out

typedef unsigned short u16;
typedef float floatx4 __attribute__((ext_vector_type(4)));
typedef short shortx8 __attribute__((ext_vector_type(8)));

#define T_ 1024
#define H_ 1024

__device__ __forceinline__ float bf2f(u16 v) {
    return __uint_as_float(((unsigned)v) << 16);
}
__device__ __forceinline__ u16 f2bf(float f) {  // round-to-nearest-even
    unsigned u = __float_as_uint(f);
    return (u16)((u + 0x7fffu + ((u >> 16) & 1u)) >> 16);
}
__device__ __forceinline__ void async16(const void* g, void* l) {
    __builtin_amdgcn_global_load_lds(
        (__attribute__((address_space(1))) void*)g,
        (__attribute__((address_space(3))) void*)l, 16, 0, 0);
}
__device__ __forceinline__ void barrier_mem() {
    asm volatile("" ::: "memory");
    __builtin_amdgcn_s_barrier();
    asm volatile("" ::: "memory");
}

// ---------------- K0: fused weight-pack + message aggregation ----------------
__global__ __launch_bounds__(256)
void prep_kernel(const float* __restrict__ x, const float* __restrict__ qmask,
                 const int* __restrict__ dia_len,
                 const float* __restrict__ Wself, const float* __restrict__ Wmsg,
                 const float* __restrict__ Wout,
                 u16* __restrict__ xcat, u16* __restrict__ wt_cat,
                 u16* __restrict__ wt_out)
{
    __shared__ u16 sx[32][1024];  // 64 KiB (transpose path reuses a corner)
    const int tid = threadIdx.x;
    const int bx = blockIdx.x;

    if (bx >= 512) {
        // ---- transpose + bf16 pack of one 32x32 weight tile ----
        const int id = bx - 512;            // 0..3071
        const int wid = id >> 10;           // 0..2
        const int rest = id & 1023;
        const int n0 = (rest & 31) * 32, k0 = (rest >> 5) * 32;
        const float* src = (wid == 0) ? Wself : ((wid == 1) ? Wmsg : Wout);
        float (*s)[33] = reinterpret_cast<float (*)[33]>(&sx[0][0]);
        const int tx = tid & 31, ty = tid >> 5;  // 32x8
#pragma unroll
        for (int i = 0; i < 4; ++i) {
            int k = k0 + ty + 8 * i;
            s[ty + 8 * i][tx] = src[(size_t)k * H_ + n0 + tx];
        }
        __syncthreads();
#pragma unroll
        for (int i = 0; i < 4; ++i) {
            int n = n0 + ty + 8 * i;
            u16 v = f2bf(s[tx][ty + 8 * i]);
            if (wid < 2) wt_cat[(size_t)n * 2048 + wid * 1024 + k0 + tx] = v;
            else         wt_out[(size_t)n * 1024 + k0 + tx] = v;
        }
        return;
    }

    // ---- msg_pack: stage 32 rows (halo 8 each side) as bf16 in LDS ----
    const int b = bx >> 6;
    const int t0 = (bx & 63) * 16;
    const int dlen = dia_len[b];
    const int c4 = tid * 4;
    const float* xb = x + (size_t)b * T_ * H_;

    unsigned spkmask = 0;
#pragma unroll 4
    for (int r = 0; r < 32; ++r) {
        int row = t0 - 8 + r;
        row = row < 0 ? 0 : (row > T_ - 1 ? T_ - 1 : row);
        const float* q = qmask + ((size_t)b * T_ + row) * 2;
        spkmask |= (q[1] > q[0] ? 1u : 0u) << r;
        float4 v = *(const float4*)(xb + (size_t)row * H_ + c4);
        ushort4 u;
        u.x = f2bf(v.x); u.y = f2bf(v.y); u.z = f2bf(v.z); u.w = f2bf(v.w);
        *(ushort4*)&sx[r][c4] = u;
    }
    __syncthreads();

    for (int lt = 0; lt < 16; ++lt) {
        const int t = t0 + lt;
        const unsigned cs = (spkmask >> (lt + 8)) & 1u;
        float a0 = 0.f, a1 = 0.f, a2 = 0.f, a3 = 0.f;
        int cnt = 0;
#pragma unroll
        for (int o = 0; o < 17; ++o) {
            const int idx = t + o - 8;
            if (idx >= 0 && idx < dlen) {  // block-uniform branch
                const float w = (((spkmask >> (lt + o)) & 1u) == cs) ? 1.0f : 0.5f;
                ++cnt;
                ushort4 u = *(const ushort4*)&sx[lt + o][c4];
                a0 += w * bf2f(u.x); a1 += w * bf2f(u.y);
                a2 += w * bf2f(u.z); a3 += w * bf2f(u.w);
            }
        }
        const float inv = 1.0f / (float)(cnt > 0 ? cnt : 1);
        ushort4 m;
        m.x = f2bf(a0 * inv); m.y = f2bf(a1 * inv);
        m.z = f2bf(a2 * inv); m.w = f2bf(a3 * inv);
        const size_t rowg = (size_t)b * T_ + t;
        *(ushort4*)&xcat[rowg * 2048 + 1024 + c4] = m;
        *(ushort4*)&xcat[rowg * 2048 + c4] = *(const ushort4*)&sx[lt + 8][c4];
    }
}

// ---------------- K1/K2: bf16 MFMA GEMM (r6 K-loop + coalesced epilogue) -----
// A: M x K row-major bf16; Bt: N x K row-major bf16 (N-major).
// LDS swizzle (T2): logical (row, 16B-slot s) lives at LDS slot s^(row&7).
template <int K, int EPI>
__global__ __launch_bounds__(512, 4)
void gemm_bt(const u16* __restrict__ A, const u16* __restrict__ Bt,
             const float* __restrict__ bias1, const float* __restrict__ bias2,
             const float* __restrict__ X, const int* __restrict__ dia_len,
             u16* __restrict__ Rout, float* __restrict__ Zout)
{
    constexpr int NT = K / 64;
    static_assert(NT >= 2, "need >=2 K-tiles");
    __shared__ u16 sA[2][128 * 64];  // 32 KiB
    __shared__ u16 sB[2][128 * 64];  // 32 KiB
    const int tid = threadIdx.x;

    // T1: XCD-aware block map (verified ~ideal FETCH in r3-r7).
    const int bid = blockIdx.x;
    const int xcd = bid & 7, li = bid >> 3;     // li in [0,64)
    const int mt = xcd * 8 + (li >> 3);         // 0..63
    const int nt = li & 7;                      // 0..7
    const int bm = mt * 128, bn = nt * 128;

    const int wave = tid >> 6, lane = tid & 63;
    const int wr = wave >> 1, wc = wave & 1;    // 4M x 2N waves, 32x64 C each
    const int lrow = lane & 15, lq = lane >> 4;

    // ---- staging (global -> LDS), pre-swizzled source ----
    const int srow = tid >> 3;                  // 0..63
    const int sl   = (tid & 7) ^ (srow & 7);    // swizzled 16B slot in row
    const u16* Asrc = A + (size_t)(bm + srow) * K + sl * 8;
    const u16* Bsrc = Bt + (size_t)(bn + srow) * K + sl * 8;

    auto stage = [&](int t, int buf) {          // 4 async16 per thread
        const int k0 = t * 64;
        async16(Asrc + k0,                    &sA[buf][tid * 8]);
        async16(Asrc + (size_t)64 * K + k0,   &sA[buf][4096 + tid * 8]);
        async16(Bsrc + k0,                    &sB[buf][tid * 8]);
        async16(Bsrc + (size_t)64 * K + k0,   &sB[buf][4096 + tid * 8]);
    };

    floatx4 acc[2][4];
#pragma unroll
    for (int i = 0; i < 2; ++i)
#pragma unroll
        for (int j = 0; j < 4; ++j)
            acc[i][j] = (floatx4){0.f, 0.f, 0.f, 0.f};

    // ---- compute-side LDS read offsets (elements) ----
    const int xk = lrow & 7;
    const int paBase = (wr * 32 + lrow) * 64;
    const int pbBase = (wc * 64 + lrow) * 64;
    const int s0 = (lq ^ xk) * 8;               // k-half 0 swizzled slot
    const int s1 = ((4 + lq) ^ xk) * 8;         // k-half 1

    // ---- prologue: both slots in flight; wait tile 0 only ----
    stage(0, 0);
    stage(1, 1);
    asm volatile("s_waitcnt vmcnt(4)" ::: "memory");  // tile 0 landed
    barrier_mem();

    for (int t = 0; t < NT; ++t) {
        if (t >= 1 && t + 1 < NT) stage(t + 1, (t + 1) & 1);

        const u16* curA = &sA[t & 1][0];
        const u16* curB = &sB[t & 1][0];
        shortx8 a0[2], a1[2], b0[4], b1[4];
#pragma unroll
        for (int j = 0; j < 4; ++j)
            b0[j] = *(const shortx8*)(curB + pbBase + j * 1024 + s0);
#pragma unroll
        for (int i = 0; i < 2; ++i)
            a0[i] = *(const shortx8*)(curA + paBase + i * 1024 + s0);
#pragma unroll
        for (int j = 0; j < 4; ++j)
            b1[j] = *(const shortx8*)(curB + pbBase + j * 1024 + s1);
#pragma unroll
        for (int i = 0; i < 2; ++i)
            a1[i] = *(const shortx8*)(curA + paBase + i * 1024 + s1);

        __builtin_amdgcn_s_setprio(1);
#pragma unroll
        for (int i = 0; i < 2; ++i)
#pragma unroll
            for (int j = 0; j < 4; ++j)
                acc[i][j] = __builtin_amdgcn_mfma_f32_16x16x32_bf16(
                    a0[i], b0[j], acc[i][j], 0, 0, 0);
#pragma unroll
        for (int i = 0; i < 2; ++i)
#pragma unroll
            for (int j = 0; j < 4; ++j)
                acc[i][j] = __builtin_amdgcn_mfma_f32_16x16x32_bf16(
                    a1[i], b1[j], acc[i][j], 0, 0, 0);
        __builtin_amdgcn_s_setprio(0);

        if (t + 1 < NT) {
            asm volatile("s_waitcnt vmcnt(0)" ::: "memory");
            barrier_mem();  // also WAR-protects the next stage()
        }
    }

    // ---- epilogue: coalesced via LDS restage, 4 slices of 32 rows ----------
    // NOTE: __syncthreads() here (NOT bare s_barrier) — ds_writes must be
    // lgkmcnt-drained before cross-wave ds_reads (r9 race).
    __syncthreads();
    const int dl = (EPI == 1) ? dia_len[bm >> 10] : 0;  // b uniform per block

    if (EPI == 1) {
        u16* eh = (u16*)&sA[0][0];               // 32 x 136 u16 tile (8.5 KB)
        const int lr0 = tid >> 4, seg = tid & 15;
        for (int s = 0; s < 4; ++s) {
            if (wr == s) {
#pragma unroll
                for (int i = 0; i < 2; ++i)
#pragma unroll
                    for (int j = 0; j < 4; ++j) {
                        const int lc = wc * 64 + j * 16 + lrow;
                        const float bb = bias1[bn + lc] + bias2[bn + lc];
#pragma unroll
                        for (int r = 0; r < 4; ++r) {
                            const int lr = i * 16 + lq * 4 + r;
                            eh[lr * 136 + lc] =
                                f2bf(fmaxf(acc[i][j][r] + bb, 0.f));
                        }
                    }
            }
            __syncthreads();
            {
                const int row = bm + s * 32 + lr0;
                const int gcol = bn + seg * 8;
                shortx8 w = *(const shortx8*)&eh[lr0 * 136 + seg * 8];
                if ((row & (T_ - 1)) >= dl) {   // substitute with relu(x)
                    const float* xp = X + (size_t)row * H_ + gcol;
                    float4 x0 = *(const float4*)xp;
                    float4 x1 = *(const float4*)(xp + 4);
                    w[0] = (short)f2bf(fmaxf(x0.x, 0.f));
                    w[1] = (short)f2bf(fmaxf(x0.y, 0.f));
                    w[2] = (short)f2bf(fmaxf(x0.z, 0.f));
                    w[3] = (short)f2bf(fmaxf(x0.w, 0.f));
                    w[4] = (short)f2bf(fmaxf(x1.x, 0.f));
                    w[5] = (short)f2bf(fmaxf(x1.y, 0.f));
                    w[6] = (short)f2bf(fmaxf(x1.z, 0.f));
                    w[7] = (short)f2bf(fmaxf(x1.w, 0.f));
                }
                *(shortx8*)&Rout[(size_t)row * H_ + gcol] = w;
            }
            __syncthreads();
        }
    } else {
        float* ef = (float*)&sA[0][0];           // 32 x 132 f32 tile (16.9 KB)
        for (int s = 0; s < 4; ++s) {
            if (wr == s) {
#pragma unroll
                for (int i = 0; i < 2; ++i)
#pragma unroll
                    for (int j = 0; j < 4; ++j) {
                        const int lc = wc * 64 + j * 16 + lrow;
                        const float bb = bias1[bn + lc];
#pragma unroll
                        for (int r = 0; r < 4; ++r) {
                            const int lr = i * 16 + lq * 4 + r;
                            ef[lr * 132 + lc] = acc[i][j][r] + bb;
                        }
                    }
            }
            __syncthreads();
#pragma unroll
            for (int k = 0; k < 2; ++k) {
                const int idx = tid + k * 512;
                const int lr = idx >> 5, seg = idx & 31;
                const int row = bm + s * 32 + lr;
                const int gcol = bn + seg * 4;
                float4 zv = *(const float4*)&ef[lr * 132 + seg * 4];
                float4 xv = *(const float4*)(X + (size_t)row * H_ + gcol);
                zv.x += xv.x; zv.y += xv.y; zv.z += xv.z; zv.w += xv.w;
                *(float4*)(Zout + (size_t)row * H_ + gcol) = zv;
            }
            __syncthreads();
        }
    }
}

// ---------------- K3: LayerNorm ---------------------------------------------
__global__ __launch_bounds__(256)
void ln_kernel(const float* __restrict__ Z, const float* __restrict__ gamma,
               const float* __restrict__ beta, float* __restrict__ out)
{
    const int row = blockIdx.x;
    const int tid = threadIdx.x;
    const size_t base = (size_t)row * H_ + tid * 4;
    float4 v = *(const float4*)(Z + base);
    float s = v.x + v.y + v.z + v.w;
    float q = v.x * v.x + v.y * v.y + v.z * v.z + v.w * v.w;
#pragma unroll
    for (int off = 32; off > 0; off >>= 1) {
        s += __shfl_down(s, off);
        q += __shfl_down(q, off);
    }
    __shared__ float ps[4], pq[4];
    const int wave = tid >> 6, lane = tid & 63;
    if (lane == 0) { ps[wave] = s; pq[wave] = q; }
    __syncthreads();
    const float S = ps[0] + ps[1] + ps[2] + ps[3];
    const float Q = pq[0] + pq[1] + pq[2] + pq[3];
    const float mean = S * (1.0f / 1024.0f);
    const float var = Q * (1.0f / 1024.0f) - mean * mean;
    const float inv = rsqrtf(var + 1e-5f);
    float4 g = *(const float4*)(gamma + tid * 4);
    float4 bt = *(const float4*)(beta + tid * 4);
    float4 o;
    o.x = g.x * (v.x - mean) * inv + bt.x;
    o.y = g.y * (v.y - mean) * inv + bt.y;
    o.z = g.z * (v.z - mean) * inv + bt.z;
    o.w = g.w * (v.w - mean) * inv + bt.w;
    *(float4*)(out + base) = o;
}

// ---------------- launcher ---------------------------------------------------
extern "C" void kernel_launch(void* const* d_in, const int* in_sizes, int n_in,
                              void* d_out, int out_size, void* d_ws, size_t ws_size,
                              hipStream_t stream)
{
    (void)in_sizes; (void)n_in; (void)out_size; (void)ws_size;
    const float* x       = (const float*)d_in[0];
    const float* qmask   = (const float*)d_in[1];
    const int*   dia_len = (const int*)d_in[2];
    const float* W_msg   = (const float*)d_in[5];
    const float* b_msg   = (const float*)d_in[6];
    const float* W_self  = (const float*)d_in[7];
    const float* b_self  = (const float*)d_in[8];
    const float* W_out   = (const float*)d_in[9];
    const float* b_out   = (const float*)d_in[10];
    const float* gamma   = (const float*)d_in[11];
    const float* beta    = (const float*)d_in[12];
    float* out = (float*)d_out;

    char* ws = (char*)d_ws;
    u16*   xcat   = (u16*)ws;                           // 32 MiB
    u16*   rbuf   = (u16*)(ws + (size_t)(32u << 20));   // 16 MiB
    u16*   wt_cat = (u16*)(ws + (size_t)(48u << 20));   // 4 MiB
    u16*   wt_out = (u16*)(ws + (size_t)(52u << 20));   // 2 MiB
    float* zbuf   = (float*)ws;                         // alias xcat (safe: GEMM2 no longer reads xcat)

    prep_kernel<<<dim3(3584), 256, 0, stream>>>(x, qmask, dia_len,
                                                W_self, W_msg, W_out,
                                                xcat, wt_cat, wt_out);
    gemm_bt<2048, 1><<<dim3(512), 512, 0, stream>>>(xcat, wt_cat, b_self, b_msg,
                                                    x, dia_len, rbuf, nullptr);
    gemm_bt<1024, 2><<<dim3(512), 512, 0, stream>>>(rbuf, wt_out, b_out, nullptr,
                                                    x, nullptr, nullptr, zbuf);
    ln_kernel<<<dim3(8192), 256, 0, stream>>>(zbuf, gamma, beta, out);
}

// Round 11
// 202.576 us; speedup vs baseline: 1.6943x; 1.0050x over previous
//
#include <hip/hip_runtime.h>

// SimpleDialogGNN on MI355X.
// Pipeline (4 launches):
//   K0 prep_kernel    : fused {transpose_pack + msg_pack}
//   K1 gemm<2048,EPI1>: h = xcat @ wt_cat^T + biases; relu/substitute -> rbuf
//   K2 gemm<1024,EPI2>: z = x + rbuf @ wt_out^T + b_out -> fp32 zbuf
//   K3 ln_kernel      : LayerNorm(z) * gamma + beta -> out
//
// GEMM core (this round): r6's proven K-loop skeleton (128x128, BK=64,
// 2-slot dbuf, stage-at-top, one vmcnt(0)+barrier per body, T2 swizzle,
// T1 XCD map, 512 thr, 2 blocks/CU) but with SPLIT-K WAVE GROUPS:
// 8 waves = 2 k-groups x (2M x 2N); group g reads only k-half g of each
// staged tile; wave tile 64x64, acc[4][4]. Per body: 64 ds_read_b128
// (was 96, -33% on the measured-dominant LDS pipe; r7 showed 73.7k cyc
// LDS vs 33k MFMA per CU), same 128 MFMA. Partial sums merged in the
// epilogue through an LDS tile (group0 writes +bias, group1 adds), then
// all 512 threads do coalesced global I/O (keeps r10's gemm2 win and
// restores gemm1's store path without the r10 restage overhead).
//
// ws layout: [0,32M) xcat (bf16, aliased by zbuf fp32 after GEMM1)
//            [32M,48M) rbuf  [48M,52M) wt_cat  [52M,54M) wt_out

typedef unsigned short u16;
typedef float floatx4 __attribute__((ext_vector_type(4)));
typedef short shortx8 __attribute__((ext_vector_type(8)));

#define T_ 1024
#define H_ 1024

__device__ __forceinline__ float bf2f(u16 v) {
    return __uint_as_float(((unsigned)v) << 16);
}
__device__ __forceinline__ u16 f2bf(float f) {  // round-to-nearest-even
    unsigned u = __float_as_uint(f);
    return (u16)((u + 0x7fffu + ((u >> 16) & 1u)) >> 16);
}
__device__ __forceinline__ void async16(const void* g, void* l) {
    __builtin_amdgcn_global_load_lds(
        (__attribute__((address_space(1))) void*)g,
        (__attribute__((address_space(3))) void*)l, 16, 0, 0);
}
__device__ __forceinline__ void barrier_mem() {
    asm volatile("" ::: "memory");
    __builtin_amdgcn_s_barrier();
    asm volatile("" ::: "memory");
}

// ---------------- K0: fused weight-pack + message aggregation ----------------
__global__ __launch_bounds__(256)
void prep_kernel(const float* __restrict__ x, const float* __restrict__ qmask,
                 const int* __restrict__ dia_len,
                 const float* __restrict__ Wself, const float* __restrict__ Wmsg,
                 const float* __restrict__ Wout,
                 u16* __restrict__ xcat, u16* __restrict__ wt_cat,
                 u16* __restrict__ wt_out)
{
    __shared__ u16 sx[32][1024];  // 64 KiB (transpose path reuses a corner)
    const int tid = threadIdx.x;
    const int bx = blockIdx.x;

    if (bx >= 512) {
        // ---- transpose + bf16 pack of one 32x32 weight tile ----
        const int id = bx - 512;            // 0..3071
        const int wid = id >> 10;           // 0..2
        const int rest = id & 1023;
        const int n0 = (rest & 31) * 32, k0 = (rest >> 5) * 32;
        const float* src = (wid == 0) ? Wself : ((wid == 1) ? Wmsg : Wout);
        float (*s)[33] = reinterpret_cast<float (*)[33]>(&sx[0][0]);
        const int tx = tid & 31, ty = tid >> 5;  // 32x8
#pragma unroll
        for (int i = 0; i < 4; ++i) {
            int k = k0 + ty + 8 * i;
            s[ty + 8 * i][tx] = src[(size_t)k * H_ + n0 + tx];
        }
        __syncthreads();
#pragma unroll
        for (int i = 0; i < 4; ++i) {
            int n = n0 + ty + 8 * i;
            u16 v = f2bf(s[tx][ty + 8 * i]);
            if (wid < 2) wt_cat[(size_t)n * 2048 + wid * 1024 + k0 + tx] = v;
            else         wt_out[(size_t)n * 1024 + k0 + tx] = v;
        }
        return;
    }

    // ---- msg_pack: stage 32 rows (halo 8 each side) as bf16 in LDS ----
    const int b = bx >> 6;
    const int t0 = (bx & 63) * 16;
    const int dlen = dia_len[b];
    const int c4 = tid * 4;
    const float* xb = x + (size_t)b * T_ * H_;

    unsigned spkmask = 0;
#pragma unroll 4
    for (int r = 0; r < 32; ++r) {
        int row = t0 - 8 + r;
        row = row < 0 ? 0 : (row > T_ - 1 ? T_ - 1 : row);
        const float* q = qmask + ((size_t)b * T_ + row) * 2;
        spkmask |= (q[1] > q[0] ? 1u : 0u) << r;
        float4 v = *(const float4*)(xb + (size_t)row * H_ + c4);
        ushort4 u;
        u.x = f2bf(v.x); u.y = f2bf(v.y); u.z = f2bf(v.z); u.w = f2bf(v.w);
        *(ushort4*)&sx[r][c4] = u;
    }
    __syncthreads();

    for (int lt = 0; lt < 16; ++lt) {
        const int t = t0 + lt;
        const unsigned cs = (spkmask >> (lt + 8)) & 1u;
        float a0 = 0.f, a1 = 0.f, a2 = 0.f, a3 = 0.f;
        int cnt = 0;
#pragma unroll
        for (int o = 0; o < 17; ++o) {
            const int idx = t + o - 8;
            if (idx >= 0 && idx < dlen) {  // block-uniform branch
                const float w = (((spkmask >> (lt + o)) & 1u) == cs) ? 1.0f : 0.5f;
                ++cnt;
                ushort4 u = *(const ushort4*)&sx[lt + o][c4];
                a0 += w * bf2f(u.x); a1 += w * bf2f(u.y);
                a2 += w * bf2f(u.z); a3 += w * bf2f(u.w);
            }
        }
        const float inv = 1.0f / (float)(cnt > 0 ? cnt : 1);
        ushort4 m;
        m.x = f2bf(a0 * inv); m.y = f2bf(a1 * inv);
        m.z = f2bf(a2 * inv); m.w = f2bf(a3 * inv);
        const size_t rowg = (size_t)b * T_ + t;
        *(ushort4*)&xcat[rowg * 2048 + 1024 + c4] = m;
        *(ushort4*)&xcat[rowg * 2048 + c4] = *(const ushort4*)&sx[lt + 8][c4];
    }
}

// ---------------- K1/K2: bf16 MFMA GEMM, split-K wave groups -----------------
// A: M x K row-major bf16; Bt: N x K row-major bf16 (N-major).
// LDS swizzle (T2): logical (row, 16B-slot s) lives at LDS slot s^(row&7).
template <int K, int EPI>
__global__ __launch_bounds__(512, 4)
void gemm_bt(const u16* __restrict__ A, const u16* __restrict__ Bt,
             const float* __restrict__ bias1, const float* __restrict__ bias2,
             const float* __restrict__ X, const int* __restrict__ dia_len,
             u16* __restrict__ Rout, float* __restrict__ Zout)
{
    constexpr int NT = K / 64;
    static_assert(NT >= 2, "need >=2 K-tiles");
    __shared__ char smem[65536];
    u16* sA = (u16*)smem;             // 2 slots x 128x64 u16 (32 KiB)
    u16* sB = (u16*)(smem + 32768);   // 2 slots x 128x64 u16 (32 KiB)
    float* ef = (float*)smem;         // epilogue merge tile 64x132 (33.8 KiB)
    const int tid = threadIdx.x;

    // T1: XCD-aware block map (verified ~ideal FETCH in r3-r10).
    const int bid = blockIdx.x;
    const int xcd = bid & 7, li = bid >> 3;     // li in [0,64)
    const int mt = xcd * 8 + (li >> 3);         // 0..63
    const int nt = li & 7;                      // 0..7
    const int bm = mt * 128, bn = nt * 128;

    const int wave = tid >> 6, lane = tid & 63;
    const int kg = wave >> 2;                   // k-group: 0 -> k 0..31, 1 -> 32..63
    const int wr = (wave >> 1) & 1, wc = wave & 1;  // 2M x 2N, 64x64 C each
    const int lrow = lane & 15, lq = lane >> 4;

    // ---- staging (global -> LDS), pre-swizzled source (r6-identical) ----
    const int srow = tid >> 3;                  // 0..63
    const int sl   = (tid & 7) ^ (srow & 7);    // swizzled 16B slot in row
    const u16* Asrc = A + (size_t)(bm + srow) * K + sl * 8;
    const u16* Bsrc = Bt + (size_t)(bn + srow) * K + sl * 8;

    auto stage = [&](int t, int buf) {          // 4 async16 per thread
        const int k0 = t * 64;
        async16(Asrc + k0,                  sA + buf * 8192 + tid * 8);
        async16(Asrc + (size_t)64 * K + k0, sA + buf * 8192 + 4096 + tid * 8);
        async16(Bsrc + k0,                  sB + buf * 8192 + tid * 8);
        async16(Bsrc + (size_t)64 * K + k0, sB + buf * 8192 + 4096 + tid * 8);
    };

    floatx4 acc[4][4];
#pragma unroll
    for (int i = 0; i < 4; ++i)
#pragma unroll
        for (int j = 0; j < 4; ++j)
            acc[i][j] = (floatx4){0.f, 0.f, 0.f, 0.f};

    // ---- compute-side LDS read offsets (elements, swizzled, k-group) ----
    const int xk = lrow & 7;
    const int ks = ((kg * 4 + lq) ^ xk) * 8;    // my k-half's 16B slot
    int aOff[4], bOff[4];
#pragma unroll
    for (int i = 0; i < 4; ++i)
        aOff[i] = (wr * 64 + i * 16 + lrow) * 64 + ks;
#pragma unroll
    for (int j = 0; j < 4; ++j)
        bOff[j] = (wc * 64 + j * 16 + lrow) * 64 + ks;

    // ---- prologue: both slots in flight; wait tile 0 only ----
    stage(0, 0);
    stage(1, 1);
    asm volatile("s_waitcnt vmcnt(4)" ::: "memory");  // tile 0 landed
    barrier_mem();

    for (int t = 0; t < NT; ++t) {
        if (t >= 1 && t + 1 < NT) stage(t + 1, (t + 1) & 1);

        const u16* cA = sA + (t & 1) * 8192;
        const u16* cB = sB + (t & 1) * 8192;
        shortx8 av[4], bv[4];
#pragma unroll
        for (int j = 0; j < 4; ++j) bv[j] = *(const shortx8*)(cB + bOff[j]);
#pragma unroll
        for (int i = 0; i < 4; ++i) av[i] = *(const shortx8*)(cA + aOff[i]);

        __builtin_amdgcn_s_setprio(1);
#pragma unroll
        for (int i = 0; i < 4; ++i)
#pragma unroll
            for (int j = 0; j < 4; ++j)
                acc[i][j] = __builtin_amdgcn_mfma_f32_16x16x32_bf16(
                    av[i], bv[j], acc[i][j], 0, 0, 0);
        __builtin_amdgcn_s_setprio(0);

        if (t + 1 < NT) {
            asm volatile("s_waitcnt vmcnt(0)" ::: "memory");
            barrier_mem();  // also WAR-protects the next stage()
        }
    }

    // ---- epilogue: merge k-groups in LDS, coalesced global I/O -------------
    __syncthreads();  // all waves done reading sA/sB; ef may alias
    const int dl = (EPI == 1) ? dia_len[bm >> 10] : 0;  // b uniform per block

    for (int s = 0; s < 2; ++s) {   // two 64-row slices
        if (kg == 0 && wr == s) {   // group 0 writes acc + bias
#pragma unroll
            for (int j = 0; j < 4; ++j) {
                const int lc = wc * 64 + j * 16 + lrow;
                const float bb = (EPI == 1) ? bias1[bn + lc] + bias2[bn + lc]
                                            : bias1[bn + lc];
#pragma unroll
                for (int i = 0; i < 4; ++i)
#pragma unroll
                    for (int r = 0; r < 4; ++r)
                        ef[(i * 16 + lq * 4 + r) * 132 + lc] = acc[i][j][r] + bb;
            }
        }
        __syncthreads();
        if (kg == 1 && wr == s) {   // group 1 accumulates its k-half
#pragma unroll
            for (int j = 0; j < 4; ++j) {
                const int lc = wc * 64 + j * 16 + lrow;
#pragma unroll
                for (int i = 0; i < 4; ++i)
#pragma unroll
                    for (int r = 0; r < 4; ++r)
                        ef[(i * 16 + lq * 4 + r) * 132 + lc] += acc[i][j][r];
            }
        }
        __syncthreads();
        // readback + coalesced store
        if (EPI == 1) {
            const int lr = tid >> 3, sg = tid & 7;   // 64 rows x 8 x 16-col segs
            const int row = bm + s * 64 + lr;
            const int gcol = bn + sg * 16;
            shortx8 w0, w1;
            if ((row & (T_ - 1)) < dl) {
                const float* ep = ef + lr * 132 + sg * 16;
                float4 e0 = *(const float4*)(ep);
                float4 e1 = *(const float4*)(ep + 4);
                float4 e2 = *(const float4*)(ep + 8);
                float4 e3 = *(const float4*)(ep + 12);
                w0[0] = (short)f2bf(fmaxf(e0.x, 0.f)); w0[1] = (short)f2bf(fmaxf(e0.y, 0.f));
                w0[2] = (short)f2bf(fmaxf(e0.z, 0.f)); w0[3] = (short)f2bf(fmaxf(e0.w, 0.f));
                w0[4] = (short)f2bf(fmaxf(e1.x, 0.f)); w0[5] = (short)f2bf(fmaxf(e1.y, 0.f));
                w0[6] = (short)f2bf(fmaxf(e1.z, 0.f)); w0[7] = (short)f2bf(fmaxf(e1.w, 0.f));
                w1[0] = (short)f2bf(fmaxf(e2.x, 0.f)); w1[1] = (short)f2bf(fmaxf(e2.y, 0.f));
                w1[2] = (short)f2bf(fmaxf(e2.z, 0.f)); w1[3] = (short)f2bf(fmaxf(e2.w, 0.f));
                w1[4] = (short)f2bf(fmaxf(e3.x, 0.f)); w1[5] = (short)f2bf(fmaxf(e3.y, 0.f));
                w1[6] = (short)f2bf(fmaxf(e3.z, 0.f)); w1[7] = (short)f2bf(fmaxf(e3.w, 0.f));
            } else {                 // substitute with relu(x), no h needed
                const float* xp = X + (size_t)row * H_ + gcol;
                float4 x0 = *(const float4*)(xp);
                float4 x1 = *(const float4*)(xp + 4);
                float4 x2 = *(const float4*)(xp + 8);
                float4 x3 = *(const float4*)(xp + 12);
                w0[0] = (short)f2bf(fmaxf(x0.x, 0.f)); w0[1] = (short)f2bf(fmaxf(x0.y, 0.f));
                w0[2] = (short)f2bf(fmaxf(x0.z, 0.f)); w0[3] = (short)f2bf(fmaxf(x0.w, 0.f));
                w0[4] = (short)f2bf(fmaxf(x1.x, 0.f)); w0[5] = (short)f2bf(fmaxf(x1.y, 0.f));
                w0[6] = (short)f2bf(fmaxf(x1.z, 0.f)); w0[7] = (short)f2bf(fmaxf(x1.w, 0.f));
                w1[0] = (short)f2bf(fmaxf(x2.x, 0.f)); w1[1] = (short)f2bf(fmaxf(x2.y, 0.f));
                w1[2] = (short)f2bf(fmaxf(x2.z, 0.f)); w1[3] = (short)f2bf(fmaxf(x2.w, 0.f));
                w1[4] = (short)f2bf(fmaxf(x3.x, 0.f)); w1[5] = (short)f2bf(fmaxf(x3.y, 0.f));
                w1[6] = (short)f2bf(fmaxf(x3.z, 0.f)); w1[7] = (short)f2bf(fmaxf(x3.w, 0.f));
            }
            u16* rp = Rout + (size_t)row * H_ + gcol;
            *(shortx8*)(rp) = w0;
            *(shortx8*)(rp + 8) = w1;
        } else {
#pragma unroll
            for (int k = 0; k < 4; ++k) {
                const int idx = tid + k * 512;       // 0..2047
                const int lr = idx >> 5, sg = idx & 31;
                const int row = bm + s * 64 + lr;
                const int gcol = bn + sg * 4;
                float4 zv = *(const float4*)&ef[lr * 132 + sg * 4];
                float4 xv = *(const float4*)(X + (size_t)row * H_ + gcol);
                zv.x += xv.x; zv.y += xv.y; zv.z += xv.z; zv.w += xv.w;
                *(float4*)(Zout + (size_t)row * H_ + gcol) = zv;
            }
        }
        __syncthreads();  // before next slice reuses ef
    }
}

// ---------------- K3: LayerNorm ---------------------------------------------
__global__ __launch_bounds__(256)
void ln_kernel(const float* __restrict__ Z, const float* __restrict__ gamma,
               const float* __restrict__ beta, float* __restrict__ out)
{
    const int row = blockIdx.x;
    const int tid = threadIdx.x;
    const size_t base = (size_t)row * H_ + tid * 4;
    float4 v = *(const float4*)(Z + base);
    float s = v.x + v.y + v.z + v.w;
    float q = v.x * v.x + v.y * v.y + v.z * v.z + v.w * v.w;
#pragma unroll
    for (int off = 32; off > 0; off >>= 1) {
        s += __shfl_down(s, off);
        q += __shfl_down(q, off);
    }
    __shared__ float ps[4], pq[4];
    const int wave = tid >> 6, lane = tid & 63;
    if (lane == 0) { ps[wave] = s; pq[wave] = q; }
    __syncthreads();
    const float S = ps[0] + ps[1] + ps[2] + ps[3];
    const float Q = pq[0] + pq[1] + pq[2] + pq[3];
    const float mean = S * (1.0f / 1024.0f);
    const float var = Q * (1.0f / 1024.0f) - mean * mean;
    const float inv = rsqrtf(var + 1e-5f);
    float4 g = *(const float4*)(gamma + tid * 4);
    float4 bt = *(const float4*)(beta + tid * 4);
    float4 o;
    o.x = g.x * (v.x - mean) * inv + bt.x;
    o.y = g.y * (v.y - mean) * inv + bt.y;
    o.z = g.z * (v.z - mean) * inv + bt.z;
    o.w = g.w * (v.w - mean) * inv + bt.w;
    *(float4*)(out + base) = o;
}

// ---------------- launcher ---------------------------------------------------
extern "C" void kernel_launch(void* const* d_in, const int* in_sizes, int n_in,
                              void* d_out, int out_size, void* d_ws, size_t ws_size,
                              hipStream_t stream)
{
    (void)in_sizes; (void)n_in; (void)out_size; (void)ws_size;
    const float* x       = (const float*)d_in[0];
    const float* qmask   = (const float*)d_in[1];
    const int*   dia_len = (const int*)d_in[2];
    const float* W_msg   = (const float*)d_in[5];
    const float* b_msg   = (const float*)d_in[6];
    const float* W_self  = (const float*)d_in[7];
    const float* b_self  = (const float*)d_in[8];
    const float* W_out   = (const float*)d_in[9];
    const float* b_out   = (const float*)d_in[10];
    const float* gamma   = (const float*)d_in[11];
    const float* beta    = (const float*)d_in[12];
    float* out = (float*)d_out;

    char* ws = (char*)d_ws;
    u16*   xcat   = (u16*)ws;                           // 32 MiB
    u16*   rbuf   = (u16*)(ws + (size_t)(32u << 20));   // 16 MiB
    u16*   wt_cat = (u16*)(ws + (size_t)(48u << 20));   // 4 MiB
    u16*   wt_out = (u16*)(ws + (size_t)(52u << 20));   // 2 MiB
    float* zbuf   = (float*)ws;                         // alias xcat (safe: GEMM2 no longer reads xcat)

    prep_kernel<<<dim3(3584), 256, 0, stream>>>(x, qmask, dia_len,
                                                W_self, W_msg, W_out,
                                                xcat, wt_cat, wt_out);
    gemm_bt<2048, 1><<<dim3(512), 512, 0, stream>>>(xcat, wt_cat, b_self, b_msg,
                                                    x, dia_len, rbuf, nullptr);
    gemm_bt<1024, 2><<<dim3(512), 512, 0, stream>>>(rbuf, wt_out, b_out, nullptr,
                                                    x, nullptr, nullptr, zbuf);
    ln_kernel<<<dim3(8192), 256, 0, stream>>>(zbuf, gamma, beta, out);
}